// Round 4
// baseline (224.119 us; speedup 1.0000x reference)
//
#include <hip/hip_runtime.h>
#include <hip/hip_bf16.h>

#define B_ROWS 32768

typedef unsigned short u16;
typedef unsigned int u32;
typedef float f32x4 __attribute__((ext_vector_type(4)));
typedef __bf16 bf16x8 __attribute__((ext_vector_type(8)));
typedef unsigned short u16x8 __attribute__((ext_vector_type(8)));

__device__ __forceinline__ u16 f2bf(float f){
    union { float f; u32 u; } v; v.f = f;
    return (u16)((v.u + 0x7FFFu + ((v.u >> 16) & 1u)) >> 16);
}
__device__ __forceinline__ float bf2f(u16 h){
    union { u32 u; float f; } v; v.u = ((u32)h) << 16; return v.f;
}
// v_cvt_pk_bf16_f32: dst.lo = bf16(lo), dst.hi = bf16(hi), RNE
__device__ __forceinline__ u32 cvtpk(float lo, float hi){
    u32 r;
    asm("v_cvt_pk_bf16_f32 %0, %1, %2" : "=v"(r) : "v"(lo), "v"(hi));
    return r;
}
__device__ __forceinline__ void async_cp16(void* lds_dst, const void* g_src){
    __builtin_amdgcn_global_load_lds(
        (const __attribute__((address_space(1))) unsigned int*)g_src,
        (__attribute__((address_space(3))) unsigned int*)lds_dst, 16, 0, 0);
}

// ---------------- weight cast/transpose ---------------------------------------
__global__ void cast_weights_kernel(const float* __restrict__ proj_w,
                                    const float* __restrict__ exp_w1,
                                    const float* __restrict__ exp_w2,
                                    const float* __restrict__ pre_w,
                                    const float* __restrict__ gate_w,
                                    u16* __restrict__ pimg, u16* __restrict__ w1T,
                                    u16* __restrict__ w2T, u16* __restrict__ prwT,
                                    u16* __restrict__ gwT){
    int i = blockIdx.x * 256 + threadIdx.x;
    if (i < 294912){                       // pimg [3][12][8192] (XOR-swizzled LDS image)
        int m = i / 98304, r = i % 98304;
        int c = r / 8192, rr = r % 8192;
        int col = rr >> 6, kb2 = rr & 63;
        int kb = kb2 ^ ((col & 7) << 3);
        pimg[i] = f2bf(proj_w[m*98304 + (c*64 + kb)*128 + col]);
    } else if (i < 688128){                // exp_w1T [8][128][384]
        int j = i - 294912;
        int e = j / 49152, r = j % 49152;
        int h = r / 384, k = r % 384;
        w1T[j] = f2bf(exp_w1[e*49152 + k*128 + h]);
    } else if (i < 819200){                // exp_w2T [8][128][128]
        int j = i - 688128;
        int e = j / 16384, r = j % 16384;
        int o = r / 128, k = r % 128;
        w2T[j] = f2bf(exp_w2[e*16384 + k*128 + o]);
    } else if (i < 827392){                // pre_wT [64][128]
        int j = i - 819200;
        int o = j / 128, k = j % 128;
        prwT[j] = f2bf(pre_w[k*64 + o]);
    } else if (i < 830464){                // gate_wT [8][384]
        int j = i - 827392;
        int e = j / 384, k = j % 384;
        gwT[j] = f2bf(gate_w[k*8 + e]);
    }
}

// ---------------- proj: tile 64 rows x 128 cols, BK=64, async dbuf ------------
__global__ __launch_bounds__(256, 2) void proj_kernel(
    const float* __restrict__ ft, const float* __restrict__ fa, const float* __restrict__ fv,
    const u16* __restrict__ pimg, const float* __restrict__ proj_b,
    u16* __restrict__ xq)
{
    __shared__ char lds[65536];            // 2 slots x (A 16KB + B 16KB)
    const int m = blockIdx.y;
    const float* feat = (m == 0) ? ft : (m == 1) ? fa : fv;
    const int row0 = blockIdx.x * 64;
    const int tid  = threadIdx.x;
    const int lane = tid & 63, wid = tid >> 6;
    const int wr = wid >> 1, wc = wid & 1;
    const int lr = lane & 15, q = lane >> 4, r4 = q * 4;

    u32 aoffs[4];
    #pragma unroll
    for (int i = 0; i < 4; i++){
        int P = i*4096 + wid*1024 + lane*16;
        int row = P >> 8, inner = P & 255;
        aoffs[i] = (u32)((row0 + row)*3072 + (inner ^ ((row & 7) << 4)));
    }
    const char* abase = (const char*)feat;
    const char* bbase = (const char*)pimg + (size_t)m * 196608 + wid*1024 + lane*16;
    const int ldsP = wid*1024 + lane*16;

    f32x4 acc[2][4];
    #pragma unroll
    for (int i = 0; i < 2; i++)
        #pragma unroll
        for (int j = 0; j < 4; j++) acc[i][j] = {0.f, 0.f, 0.f, 0.f};

#define STAGE(s, c) do{                                                        \
        char* la = lds + (s)*32768 + ldsP;                                     \
        char* lb = lds + (s)*32768 + 16384 + ldsP;                             \
        const char* gb = bbase + (c)*16384;                                    \
        u32 kadd = (u32)(c) << 8;                                              \
        _Pragma("unroll")                                                      \
        for (int i = 0; i < 4; i++) async_cp16(la + i*4096, abase + aoffs[i] + kadd); \
        _Pragma("unroll")                                                      \
        for (int i = 0; i < 4; i++) async_cp16(lb + i*4096, gb + i*4096);      \
    }while(0)

#define CONSUME(s) do{                                                         \
        const char* Abuf = lds + (s)*32768;                                    \
        const char* Bbuf = Abuf + 16384;                                       \
        _Pragma("unroll")                                                      \
        for (int ks = 0; ks < 2; ks++){                                        \
            bf16x8 af[2];                                                      \
            _Pragma("unroll")                                                  \
            for (int mi = 0; mi < 2; mi++){                                    \
                int row = wr*32 + mi*16 + lr;                                  \
                int aoff = row*256 + ((ks*128 + q*32) ^ ((row & 7) << 4));     \
                f32x4 a0 = *(const f32x4*)(Abuf + aoff);                       \
                f32x4 a1 = *(const f32x4*)(Abuf + (aoff ^ 16));                \
                union { u32 w[4]; bf16x8 v; } u;                               \
                u.w[0] = cvtpk(a0.x, a0.y); u.w[1] = cvtpk(a0.z, a0.w);        \
                u.w[2] = cvtpk(a1.x, a1.y); u.w[3] = cvtpk(a1.z, a1.w);        \
                af[mi] = u.v;                                                  \
            }                                                                  \
            _Pragma("unroll")                                                  \
            for (int ni = 0; ni < 4; ni++){                                    \
                int col = wc*64 + ni*16 + lr;                                  \
                int boff = col*128 + ((ks*64 + q*16) ^ ((col & 7) << 4));      \
                bf16x8 bf = *(const bf16x8*)(Bbuf + boff);                     \
                acc[0][ni] = __builtin_amdgcn_mfma_f32_16x16x32_bf16(af[0], bf, acc[0][ni], 0, 0, 0); \
                acc[1][ni] = __builtin_amdgcn_mfma_f32_16x16x32_bf16(af[1], bf, acc[1][ni], 0, 0, 0); \
            }                                                                  \
        }                                                                      \
    }while(0)

    STAGE(0, 0);
    int cur = 0;
    for (int t = 0; t < 11; t++){
        __builtin_amdgcn_sched_barrier(0);
        __builtin_amdgcn_s_barrier();
        STAGE(cur ^ 1, t + 1);
        asm volatile("s_waitcnt vmcnt(8)" ::: "memory");
        __builtin_amdgcn_s_barrier();
        __builtin_amdgcn_sched_barrier(0);
        CONSUME(cur);
        cur ^= 1;
    }
    __builtin_amdgcn_sched_barrier(0);
    __builtin_amdgcn_s_barrier();
    asm volatile("s_waitcnt vmcnt(0)" ::: "memory");
    __builtin_amdgcn_s_barrier();
    __builtin_amdgcn_sched_barrier(0);
    CONSUME(cur);
#undef STAGE
#undef CONSUME

    __syncthreads();
    u16 (*Os)[136] = (u16(*)[136])lds;
    #pragma unroll
    for (int mi = 0; mi < 2; mi++)
        #pragma unroll
        for (int ni = 0; ni < 4; ni++){
            int col = wc*64 + ni*16 + lr;
            float bias = proj_b[m*128 + col];
            #pragma unroll
            for (int j = 0; j < 4; j++)
                Os[wr*32 + mi*16 + r4 + j][col] = f2bf(acc[mi][ni][j] + bias);
        }
    __syncthreads();
    {
        int row = tid >> 2, cg = (tid & 3) * 32;
        u16* dst = xq + (size_t)(row0 + row) * 384 + m*128 + cg;
        #pragma unroll
        for (int i = 0; i < 4; i++)
            *(uint4*)(dst + i*8) = *(uint4*)&Os[row][cg + i*8];
    }
}

// ---------------- fused gate + experts + pre + head ---------------------------
// B-fragments (weights) loaded DIRECTLY from global (L2-resident, [col][k]
// layout = one dwordx4 per lane) with 1-step register prefetch. No Ws stage,
// barriers only at expert boundaries (~20 total vs ~270).
__global__ __launch_bounds__(256, 2) void moe_kernel(
    const u16* __restrict__ xq,
    const u16* __restrict__ w1T, const u16* __restrict__ w2T, const u16* __restrict__ prwT,
    const u16* __restrict__ gwT, const float* __restrict__ gate_b,
    const float* __restrict__ exp_b1, const float* __restrict__ exp_b2,
    const float* __restrict__ pre_b, const float* __restrict__ head_w, const float* __restrict__ head_b,
    float* __restrict__ out)
{
    __shared__ u16  Xs[64][392];   // x tile, full K=384 (+8 pad)
    __shared__ u16  Hs[64][136];   // h tile / fused tile (+8 pad)
    __shared__ float GW[64][8];    // gate weights

    const int row0 = blockIdx.x * 64;
    const int tid  = threadIdx.x;
    const int lane = tid & 63, wid = tid >> 6;
    const int wr = wid >> 1, wc = wid & 1;
    const int lr = lane & 15, q = lane >> 4;
    const int lk8 = q * 8, r4 = q * 4;

    {   // load x tile: 4 threads per row, 96 cols each
        const int xr = tid >> 2, xc = (tid & 3) * 96;
        const u16* xg = xq + (size_t)(row0 + xr) * 384 + xc;
        #pragma unroll
        for (int i = 0; i < 12; i++)
            *(uint4*)&Xs[xr][xc + i*8] = *(const uint4*)(xg + i*8);
    }
    __syncthreads();

    // ---- gate logits + softmax ----
    for (int task = tid; task < 512; task += 256){
        int r = task >> 3, e = task & 7;
        float s = gate_b[e];
        const u16* gw = gwT + e * 384;
        for (int k = 0; k < 384; k += 8){
            u16x8 xv = *(const u16x8*)&Xs[r][k];
            u16x8 wv = *(const u16x8*)(gw + k);
            #pragma unroll
            for (int j = 0; j < 8; j++) s += bf2f(xv[j]) * bf2f(wv[j]);
        }
        GW[r][e] = s;
    }
    __syncthreads();
    if (tid < 64){
        float v[8], mx = -1e30f;
        #pragma unroll
        for (int e = 0; e < 8; e++){ v[e] = GW[tid][e]; mx = fmaxf(mx, v[e]); }
        float sum = 0.f;
        #pragma unroll
        for (int e = 0; e < 8; e++){ v[e] = __expf(v[e] - mx); sum += v[e]; }
        float inv = 1.f / sum;
        #pragma unroll
        for (int e = 0; e < 8; e++) GW[tid][e] = v[e] * inv;
    }
    // GW visibility: wave 0 passes the next barrier only after its LDS writes
    // drain; all GW reads happen after that barrier.

    f32x4 fus[2][4];
    #pragma unroll
    for (int i = 0; i < 2; i++)
        #pragma unroll
        for (int j = 0; j < 4; j++) fus[i][j] = {0.f, 0.f, 0.f, 0.f};

    // per-lane fragment base pointers ([col][k] layout, 16B per lane)
    const u16* w1p = w1T + (size_t)(wc*64 + lr) * 384 + lk8;   // + e*49152 + ni*6144 + kt
    const u16* w2p = w2T + (size_t)(wc*64 + lr) * 128 + lk8;   // + e*16384 + ni*2048 + kt
    const u16* prp = prwT + (size_t)(wc*32 + lr) * 128 + lk8;  // + ni*2048 + kt

    for (int e = 0; e < 8; e++){
        // ---- h = relu(x @ w1_e + b1) : [64x384]x[384x128], no barriers ----
        const u16* wp = w1p + e*49152;
        bf16x8 bn[4];
        #pragma unroll
        for (int ni = 0; ni < 4; ni++) bn[ni] = *(const bf16x8*)(wp + ni*6144);
        f32x4 acc[2][4];
        #pragma unroll
        for (int i = 0; i < 2; i++)
            #pragma unroll
            for (int j = 0; j < 4; j++) acc[i][j] = {0.f, 0.f, 0.f, 0.f};
        #pragma unroll
        for (int kt = 0; kt < 384; kt += 32){
            bf16x8 bc[4];
            #pragma unroll
            for (int ni = 0; ni < 4; ni++) bc[ni] = bn[ni];
            if (kt + 32 < 384){
                #pragma unroll
                for (int ni = 0; ni < 4; ni++) bn[ni] = *(const bf16x8*)(wp + ni*6144 + kt + 32);
            }
            bf16x8 af[2];
            #pragma unroll
            for (int mi = 0; mi < 2; mi++) af[mi] = *(const bf16x8*)&Xs[wr*32 + mi*16 + lr][kt + lk8];
            #pragma unroll
            for (int mi = 0; mi < 2; mi++)
                #pragma unroll
                for (int ni = 0; ni < 4; ni++)
                    acc[mi][ni] = __builtin_amdgcn_mfma_f32_16x16x32_bf16(af[mi], bc[ni], acc[mi][ni], 0, 0, 0);
        }
        __syncthreads();   // prev expert's Hs reads done (also covers GW for e=0)
        #pragma unroll
        for (int mi = 0; mi < 2; mi++)
            #pragma unroll
            for (int ni = 0; ni < 4; ni++){
                int col = wc*64 + ni*16 + lr;
                float b1v = exp_b1[e*128 + col];
                #pragma unroll
                for (int j = 0; j < 4; j++){
                    int row = wr*32 + mi*16 + r4 + j;
                    Hs[row][col] = f2bf(fmaxf(acc[mi][ni][j] + b1v, 0.f));
                }
            }
        __syncthreads();   // Hs visible
        // ---- eo = h @ w2_e + b2 : [64x128]x[128x128], no barriers ----
        const u16* vp = w2p + e*16384;
        bf16x8 dn[4];
        #pragma unroll
        for (int ni = 0; ni < 4; ni++) dn[ni] = *(const bf16x8*)(vp + ni*2048);
        f32x4 acc2[2][4];
        #pragma unroll
        for (int i = 0; i < 2; i++)
            #pragma unroll
            for (int j = 0; j < 4; j++) acc2[i][j] = {0.f, 0.f, 0.f, 0.f};
        #pragma unroll
        for (int kt = 0; kt < 128; kt += 32){
            bf16x8 dc[4];
            #pragma unroll
            for (int ni = 0; ni < 4; ni++) dc[ni] = dn[ni];
            if (kt + 32 < 128){
                #pragma unroll
                for (int ni = 0; ni < 4; ni++) dn[ni] = *(const bf16x8*)(vp + ni*2048 + kt + 32);
            }
            bf16x8 af[2];
            #pragma unroll
            for (int mi = 0; mi < 2; mi++) af[mi] = *(const bf16x8*)&Hs[wr*32 + mi*16 + lr][kt + lk8];
            #pragma unroll
            for (int mi = 0; mi < 2; mi++)
                #pragma unroll
                for (int ni = 0; ni < 4; ni++)
                    acc2[mi][ni] = __builtin_amdgcn_mfma_f32_16x16x32_bf16(af[mi], dc[ni], acc2[mi][ni], 0, 0, 0);
        }
        // ---- fused += gw[:,e] * (eo + b2) ----
        #pragma unroll
        for (int mi = 0; mi < 2; mi++)
            #pragma unroll
            for (int ni = 0; ni < 4; ni++){
                int col = wc*64 + ni*16 + lr;
                float b2v = exp_b2[e*128 + col];
                #pragma unroll
                for (int j = 0; j < 4; j++){
                    int row = wr*32 + mi*16 + r4 + j;
                    fus[mi][ni][j] += GW[row][e] * (acc2[mi][ni][j] + b2v);
                }
            }
    }

    __syncthreads();  // all Hs reads (expert 7 w2) done before overwrite
    #pragma unroll
    for (int mi = 0; mi < 2; mi++)
        #pragma unroll
        for (int ni = 0; ni < 4; ni++)
            #pragma unroll
            for (int j = 0; j < 4; j++)
                Hs[wr*32 + mi*16 + r4 + j][wc*64 + ni*16 + lr] = f2bf(fus[mi][ni][j]);
    __syncthreads();

    // ---- penult = relu(fused @ pre_w + pre_b) : [64x128]x[128x64] ----
    f32x4 accp[2][2];
    #pragma unroll
    for (int i = 0; i < 2; i++)
        #pragma unroll
        for (int j = 0; j < 2; j++) accp[i][j] = {0.f, 0.f, 0.f, 0.f};
    bf16x8 pn[2];
    #pragma unroll
    for (int ni = 0; ni < 2; ni++) pn[ni] = *(const bf16x8*)(prp + ni*2048);
    #pragma unroll
    for (int kt = 0; kt < 128; kt += 32){
        bf16x8 pc[2];
        #pragma unroll
        for (int ni = 0; ni < 2; ni++) pc[ni] = pn[ni];
        if (kt + 32 < 128){
            #pragma unroll
            for (int ni = 0; ni < 2; ni++) pn[ni] = *(const bf16x8*)(prp + ni*2048 + kt + 32);
        }
        bf16x8 af[2];
        #pragma unroll
        for (int mi = 0; mi < 2; mi++) af[mi] = *(const bf16x8*)&Hs[wr*32 + mi*16 + lr][kt + lk8];
        #pragma unroll
        for (int mi = 0; mi < 2; mi++)
            #pragma unroll
            for (int ni = 0; ni < 2; ni++)
                accp[mi][ni] = __builtin_amdgcn_mfma_f32_16x16x32_bf16(af[mi], pc[ni], accp[mi][ni], 0, 0, 0);
    }
    // penult (f32) into Xs region (x tile dead now)
    float* Pen = (float*)&Xs[0][0];   // [64][68]
    #pragma unroll
    for (int mi = 0; mi < 2; mi++)
        #pragma unroll
        for (int ni = 0; ni < 2; ni++){
            int col = wc*32 + ni*16 + lr;
            float pbv = pre_b[col];
            #pragma unroll
            for (int j = 0; j < 4; j++){
                int row = wr*32 + mi*16 + r4 + j;
                Pen[row*68 + col] = fmaxf(accp[mi][ni][j] + pbv, 0.f);
            }
        }
    __syncthreads();
    // ---- head ----
    if (tid < 128){
        int r = tid >> 1, c = tid & 1;
        float s = head_b[c];
        for (int k = 0; k < 64; k++) s += Pen[r*68 + k] * head_w[k*2 + c];
        out[(size_t)(row0 + r)*2 + c] = s;
    }
}

extern "C" void kernel_launch(void* const* d_in, const int* in_sizes, int n_in,
                              void* d_out, int out_size, void* d_ws, size_t ws_size,
                              hipStream_t stream) {
    const float* ft     = (const float*)d_in[0];
    const float* fa     = (const float*)d_in[1];
    const float* fv     = (const float*)d_in[2];
    const float* proj_w = (const float*)d_in[3];
    const float* proj_b = (const float*)d_in[4];
    const float* exp_w1 = (const float*)d_in[5];
    const float* exp_b1 = (const float*)d_in[6];
    const float* exp_w2 = (const float*)d_in[7];
    const float* exp_b2 = (const float*)d_in[8];
    const float* gate_w = (const float*)d_in[9];
    const float* gate_b = (const float*)d_in[10];
    const float* pre_w  = (const float*)d_in[11];
    const float* pre_b  = (const float*)d_in[12];
    const float* head_w = (const float*)d_in[13];
    const float* head_b = (const float*)d_in[14];
    float* out = (float*)d_out;

    u16* xq   = (u16*)d_ws;                       // 32768*384
    u16* pimg = xq   + (size_t)B_ROWS * 384;      // 294912
    u16* w1T  = pimg + 294912;                    // 393216
    u16* w2T  = w1T + 393216;                     // 131072
    u16* prwT = w2T + 131072;                     // 8192
    u16* gwT  = prwT + 8192;                      // 3072

    cast_weights_kernel<<<3244, 256, 0, stream>>>(proj_w, exp_w1, exp_w2, pre_w, gate_w,
                                                  pimg, w1T, w2T, prwT, gwT);
    proj_kernel<<<dim3(B_ROWS/64, 3), 256, 0, stream>>>(ft, fa, fv, pimg, proj_b, xq);
    moe_kernel<<<B_ROWS/64, 256, 0, stream>>>(xq, w1T, w2T, prwT, gwT,
                                              gate_b, exp_b1, exp_b2,
                                              pre_b, head_w, head_b, out);
}

// Round 5
// 138.569 us; speedup vs baseline: 1.6174x; 1.6174x over previous
//
#include <hip/hip_runtime.h>
#include <hip/hip_bf16.h>

#define B_ROWS 32768

typedef unsigned short u16;
typedef unsigned int u32;
typedef float f32x4 __attribute__((ext_vector_type(4)));
typedef __bf16 bf16x8 __attribute__((ext_vector_type(8)));

__device__ __forceinline__ u16 f2bf(float f){
    union { float f; u32 u; } v; v.f = f;
    return (u16)((v.u + 0x7FFFu + ((v.u >> 16) & 1u)) >> 16);
}
__device__ __forceinline__ float bf2f(u16 h){
    union { u32 u; float f; } v; v.u = ((u32)h) << 16; return v.f;
}
// v_cvt_pk_bf16_f32: dst.lo = bf16(lo), dst.hi = bf16(hi), RNE
__device__ __forceinline__ u32 cvtpk(float lo, float hi){
    u32 r;
    asm("v_cvt_pk_bf16_f32 %0, %1, %2" : "=v"(r) : "v"(lo), "v"(hi));
    return r;
}
__device__ __forceinline__ void async_cp16(void* lds_dst, const void* g_src){
    __builtin_amdgcn_global_load_lds(
        (const __attribute__((address_space(1))) unsigned int*)g_src,
        (__attribute__((address_space(3))) unsigned int*)lds_dst, 16, 0, 0);
}

// ---------------- weight cast/transpose into staging-friendly images ----------
// pimg : [3][12][8192]  XOR-swizzled proj-B LDS image (unchanged from r3)
// w1img: [8][12 chunks][q:4][col:128][8]  (chunk ph covers k = ph*32 + q*8 + el)
// w2img: [8][4 chunks][q:4][col:128][8]
// prwT : [64][128] plain [o][k]
// gwimg: [16][384] zero-padded gate weights, [e][k]
__global__ void cast_weights_kernel(const float* __restrict__ proj_w,
                                    const float* __restrict__ exp_w1,
                                    const float* __restrict__ exp_w2,
                                    const float* __restrict__ pre_w,
                                    const float* __restrict__ gate_w,
                                    u16* __restrict__ pimg, u16* __restrict__ w1img,
                                    u16* __restrict__ w2img, u16* __restrict__ prwT,
                                    u16* __restrict__ gwimg){
    int i = blockIdx.x * 256 + threadIdx.x;
    if (i < 294912){                       // pimg
        int m = i / 98304, r = i % 98304;
        int c = r / 8192, rr = r % 8192;
        int col = rr >> 6, kb2 = rr & 63;
        int kb = kb2 ^ ((col & 7) << 3);
        pimg[i] = f2bf(proj_w[m*98304 + (c*64 + kb)*128 + col]);
    } else if (i < 688128){                // w1img
        int j = i - 294912;
        int e = j / 49152, r = j % 49152;
        int ph = r / 4096, rr = r % 4096;
        int q = rr >> 10, col = (rr >> 3) & 127, el = rr & 7;
        w1img[j] = f2bf(exp_w1[e*49152 + (ph*32 + q*8 + el)*128 + col]);
    } else if (i < 819200){                // w2img
        int j = i - 688128;
        int e = j / 16384, r = j % 16384;
        int c2 = r / 4096, rr = r % 4096;
        int q = rr >> 10, col = (rr >> 3) & 127, el = rr & 7;
        w2img[j] = f2bf(exp_w2[e*16384 + (c2*32 + q*8 + el)*128 + col]);
    } else if (i < 827392){                // prwT
        int j = i - 819200;
        int o = j / 128, k = j % 128;
        prwT[j] = f2bf(pre_w[k*64 + o]);
    } else if (i < 833536){                // gwimg
        int j = i - 827392;
        int e = j / 384, k = j % 384;
        gwimg[j] = (e < 8) ? f2bf(gate_w[k*8 + e]) : (u16)0;
    }
}

// ---------------- proj: tile 64 rows x 128 cols, BK=64, async dbuf ------------
// Output now written as xqimg: per 64-row block, [kt:12][q:4][row:64][16B].
__global__ __launch_bounds__(256, 2) void proj_kernel(
    const float* __restrict__ ft, const float* __restrict__ fa, const float* __restrict__ fv,
    const u16* __restrict__ pimg, const float* __restrict__ proj_b,
    u16* __restrict__ xqimg)
{
    __shared__ char lds[65536];            // 2 slots x (A 16KB + B 16KB)
    const int m = blockIdx.y;
    const float* feat = (m == 0) ? ft : (m == 1) ? fa : fv;
    const int row0 = blockIdx.x * 64;
    const int tid  = threadIdx.x;
    const int lane = tid & 63, wid = tid >> 6;
    const int wr = wid >> 1, wc = wid & 1;
    const int lr = lane & 15, q = lane >> 4, r4 = q * 4;

    u32 aoffs[4];
    #pragma unroll
    for (int i = 0; i < 4; i++){
        int P = i*4096 + wid*1024 + lane*16;
        int row = P >> 8, inner = P & 255;
        aoffs[i] = (u32)((row0 + row)*3072 + (inner ^ ((row & 7) << 4)));
    }
    const char* abase = (const char*)feat;
    const char* bbase = (const char*)pimg + (size_t)m * 196608 + wid*1024 + lane*16;
    const int ldsP = wid*1024 + lane*16;

    f32x4 acc[2][4];
    #pragma unroll
    for (int i = 0; i < 2; i++)
        #pragma unroll
        for (int j = 0; j < 4; j++) acc[i][j] = {0.f, 0.f, 0.f, 0.f};

#define STAGE(s, c) do{                                                        \
        char* la = lds + (s)*32768 + ldsP;                                     \
        char* lb = lds + (s)*32768 + 16384 + ldsP;                             \
        const char* gb = bbase + (c)*16384;                                    \
        u32 kadd = (u32)(c) << 8;                                              \
        _Pragma("unroll")                                                      \
        for (int i = 0; i < 4; i++) async_cp16(la + i*4096, abase + aoffs[i] + kadd); \
        _Pragma("unroll")                                                      \
        for (int i = 0; i < 4; i++) async_cp16(lb + i*4096, gb + i*4096);      \
    }while(0)

#define CONSUME(s) do{                                                         \
        const char* Abuf = lds + (s)*32768;                                    \
        const char* Bbuf = Abuf + 16384;                                       \
        _Pragma("unroll")                                                      \
        for (int ks = 0; ks < 2; ks++){                                        \
            bf16x8 af[2];                                                      \
            _Pragma("unroll")                                                  \
            for (int mi = 0; mi < 2; mi++){                                    \
                int row = wr*32 + mi*16 + lr;                                  \
                int aoff = row*256 + ((ks*128 + q*32) ^ ((row & 7) << 4));     \
                f32x4 a0 = *(const f32x4*)(Abuf + aoff);                       \
                f32x4 a1 = *(const f32x4*)(Abuf + (aoff ^ 16));                \
                union { u32 w[4]; bf16x8 v; } u;                               \
                u.w[0] = cvtpk(a0.x, a0.y); u.w[1] = cvtpk(a0.z, a0.w);        \
                u.w[2] = cvtpk(a1.x, a1.y); u.w[3] = cvtpk(a1.z, a1.w);        \
                af[mi] = u.v;                                                  \
            }                                                                  \
            _Pragma("unroll")                                                  \
            for (int ni = 0; ni < 4; ni++){                                    \
                int col = wc*64 + ni*16 + lr;                                  \
                int boff = col*128 + ((ks*64 + q*16) ^ ((col & 7) << 4));      \
                bf16x8 bf = *(const bf16x8*)(Bbuf + boff);                     \
                acc[0][ni] = __builtin_amdgcn_mfma_f32_16x16x32_bf16(af[0], bf, acc[0][ni], 0, 0, 0); \
                acc[1][ni] = __builtin_amdgcn_mfma_f32_16x16x32_bf16(af[1], bf, acc[1][ni], 0, 0, 0); \
            }                                                                  \
        }                                                                      \
    }while(0)

    STAGE(0, 0);
    int cur = 0;
    for (int t = 0; t < 11; t++){
        __builtin_amdgcn_sched_barrier(0);
        __builtin_amdgcn_s_barrier();
        STAGE(cur ^ 1, t + 1);
        asm volatile("s_waitcnt vmcnt(8)" ::: "memory");
        __builtin_amdgcn_s_barrier();
        __builtin_amdgcn_sched_barrier(0);
        CONSUME(cur);
        cur ^= 1;
    }
    __builtin_amdgcn_sched_barrier(0);
    __builtin_amdgcn_s_barrier();
    asm volatile("s_waitcnt vmcnt(0)" ::: "memory");
    __builtin_amdgcn_s_barrier();
    __builtin_amdgcn_sched_barrier(0);
    CONSUME(cur);
#undef STAGE
#undef CONSUME

    __syncthreads();
    u16 (*Os)[136] = (u16(*)[136])lds;
    #pragma unroll
    for (int mi = 0; mi < 2; mi++)
        #pragma unroll
        for (int ni = 0; ni < 4; ni++){
            int col = wc*64 + ni*16 + lr;
            float bias = proj_b[m*128 + col];
            #pragma unroll
            for (int j = 0; j < 4; j++)
                Os[wr*32 + mi*16 + r4 + j][col] = f2bf(acc[mi][ni][j] + bias);
        }
    __syncthreads();
    {   // write into xqimg image layout: [kt=m*4+gg][q=i][row][16B]
        int row = tid & 63, gg = tid >> 6;     // gg 0..3
        char* dst = (char*)xqimg + ((size_t)(row0 >> 6))*49152 + (m*4 + gg)*4096 + row*16;
        #pragma unroll
        for (int i = 0; i < 4; i++)
            *(uint4*)(dst + i*1024) = *(uint4*)&Os[row][(gg*4 + i)*8];
    }
}

// ---------------- fused gate + experts + pre + head ---------------------------
// M=128 tile, 512 threads (8 waves 4x2), grid 256 (1 block/CU).
// All staging via global_load_lds; 128-chunk counted-vmcnt pipeline.
#define XS_OFF   0
#define WB_OFF   98304
#define HS_OFF   114688
#define GWT_OFF  149504
#define B1_OFF   153600
#define B2_OFF   155648

__global__ __launch_bounds__(512, 2) void moe_kernel(
    const u16* __restrict__ xqimg, const u16* __restrict__ w1img, const u16* __restrict__ w2img,
    const u16* __restrict__ prwT, const u16* __restrict__ gwimg,
    const float* __restrict__ gate_b, const float* __restrict__ exp_b1, const float* __restrict__ exp_b2,
    const float* __restrict__ pre_b, const float* __restrict__ head_w, const float* __restrict__ head_b,
    float* __restrict__ out)
{
    __shared__ __align__(16) char lds[157696];
    const int tid = threadIdx.x;
    const int lane = tid & 63, wid = tid >> 6;   // 8 waves
    const int wr = wid >> 1, wc = wid & 1;       // 4 x 2
    const int lr = lane & 15, q = lane >> 4;
    const int blk = blockIdx.x;
    const char* w1b = (const char*)w1img;
    const char* w2b = (const char*)w2img;
    u16* Hs  = (u16*)(lds + HS_OFF);             // [128][136]
    u16* b1L = (u16*)(lds + B1_OFF);
    u16* b2L = (u16*)(lds + B2_OFF);

    // ---- prologue: stage Xs (12 ops) + chunk0 (1 op); biases -> LDS ----
    {
        const char* xg = (const char*)xqimg + (size_t)blk * 98304 + tid*16;
        #pragma unroll
        for (int i = 0; i < 12; i++)
            async_cp16(lds + i*8192 + tid*16, xg + i*8192);
        async_cp16(lds + WB_OFF + tid*16, w1b + tid*16);   // chunk 0 = e0/ph0
        for (int i = tid; i < 1024; i += 512){
            b1L[i] = f2bf(exp_b1[i]);
            b2L[i] = f2bf(exp_b2[i]);
        }
    }
    asm volatile("s_waitcnt vmcnt(0) lgkmcnt(0)" ::: "memory");
    __builtin_amdgcn_sched_barrier(0);
    __builtin_amdgcn_s_barrier();

    // ---- gate: one MFMA column per wave (16 rows), softmax over 8 lanes ----
    {
        f32x4 ga = {0.f, 0.f, 0.f, 0.f};
        const char* xb = lds + (wid >> 2)*49152 + ((wid & 3)*16 + lr)*16 + q*1024;
        const u16* gwp = gwimg + lr*384 + q*8;
        #pragma unroll
        for (int kt = 0; kt < 12; kt++){
            bf16x8 af = *(const bf16x8*)(xb + kt*4096);
            bf16x8 gb = *(const bf16x8*)(gwp + kt*32);
            ga = __builtin_amdgcn_mfma_f32_16x16x32_bf16(af, gb, ga, 0, 0, 0);
        }
        float gbv = gate_b[lr & 7];
        float gw4[4];
        #pragma unroll
        for (int j = 0; j < 4; j++){
            float v = ga[j] + gbv;
            float mx = v;
            mx = fmaxf(mx, __shfl_xor(mx, 1));
            mx = fmaxf(mx, __shfl_xor(mx, 2));
            mx = fmaxf(mx, __shfl_xor(mx, 4));
            float s = __expf(v - mx);
            float t = s;
            t += __shfl_xor(t, 1);
            t += __shfl_xor(t, 2);
            t += __shfl_xor(t, 4);
            gw4[j] = s / t;
        }
        if (lr < 8){
            f32x4 wv = {gw4[0], gw4[1], gw4[2], gw4[3]};
            *(f32x4*)(lds + GWT_OFF + lr*512 + (wid*16 + q*4)*4) = wv;
        }
    }
    asm volatile("s_waitcnt lgkmcnt(0)" ::: "memory");
    __builtin_amdgcn_sched_barrier(0);
    __builtin_amdgcn_s_barrier();

    // ---- expert pipeline: 128 chunks, dbuf, counted vmcnt ----
    f32x4 fus[2][4];
    #pragma unroll
    for (int i = 0; i < 2; i++)
        #pragma unroll
        for (int j = 0; j < 4; j++) fus[i][j] = {0.f, 0.f, 0.f, 0.f};
    int cur = 0;

    #pragma unroll 1
    for (int e = 0; e < 8; e++){
        f32x4 acc[2][4];
        #pragma unroll
        for (int i = 0; i < 2; i++)
            #pragma unroll
            for (int j = 0; j < 4; j++) acc[i][j] = {0.f, 0.f, 0.f, 0.f};

        #pragma unroll 1
        for (int ph = 0; ph < 12; ph++){
            __builtin_amdgcn_sched_barrier(0);
            __builtin_amdgcn_s_barrier();
            {   // stage chunk g+1 (max 124 here, always valid)
                int gn = e*16 + ph + 1;
                int en = gn >> 4, pn = gn & 15;
                const char* src = (pn < 12) ? (w1b + en*98304 + pn*8192)
                                            : (w2b + en*32768 + (pn - 12)*8192);
                async_cp16(lds + WB_OFF + (cur ^ 1)*8192 + tid*16, src + tid*16);
            }
            asm volatile("s_waitcnt vmcnt(1)" ::: "memory");
            __builtin_amdgcn_s_barrier();
            __builtin_amdgcn_sched_barrier(0);
            const char* wsl = lds + WB_OFF + cur*8192 + q*2048;
            const char* xa  = lds + (wr >> 1)*49152 + ph*4096 + q*1024;
            bf16x8 af0 = *(const bf16x8*)(xa + ((wr & 1)*32 + lr)*16);
            bf16x8 af1 = *(const bf16x8*)(xa + ((wr & 1)*32 + 16 + lr)*16);
            #pragma unroll
            for (int ni = 0; ni < 4; ni++){
                bf16x8 bf = *(const bf16x8*)(wsl + (wc*64 + ni*16 + lr)*16);
                acc[0][ni] = __builtin_amdgcn_mfma_f32_16x16x32_bf16(af0, bf, acc[0][ni], 0, 0, 0);
                acc[1][ni] = __builtin_amdgcn_mfma_f32_16x16x32_bf16(af1, bf, acc[1][ni], 0, 0, 0);
            }
            cur ^= 1;
        }
        // h = relu(acc + b1) -> Hs
        #pragma unroll
        for (int mi = 0; mi < 2; mi++)
            #pragma unroll
            for (int ni = 0; ni < 4; ni++){
                int col = wc*64 + ni*16 + lr;
                float b1v = bf2f(b1L[e*128 + col]);
                #pragma unroll
                for (int j = 0; j < 4; j++){
                    int row = wr*32 + mi*16 + q*4 + j;
                    Hs[row*136 + col] = f2bf(fmaxf(acc[mi][ni][j] + b1v, 0.f));
                }
            }
        asm volatile("s_waitcnt lgkmcnt(0)" ::: "memory");
        __builtin_amdgcn_sched_barrier(0);

        f32x4 ac2[2][4];
        #pragma unroll
        for (int i = 0; i < 2; i++)
            #pragma unroll
            for (int j = 0; j < 4; j++) ac2[i][j] = {0.f, 0.f, 0.f, 0.f};

        #pragma unroll 1
        for (int p2 = 0; p2 < 4; p2++){
            __builtin_amdgcn_sched_barrier(0);
            __builtin_amdgcn_s_barrier();
            {   // stage chunk g+1 (clamp -> dummy restage of 127 at the very end)
                int gn = e*16 + 13 + p2;
                if (gn > 127) gn = 127;
                int en = gn >> 4, pn = gn & 15;
                const char* src = (pn < 12) ? (w1b + en*98304 + pn*8192)
                                            : (w2b + en*32768 + (pn - 12)*8192);
                async_cp16(lds + WB_OFF + (cur ^ 1)*8192 + tid*16, src + tid*16);
            }
            asm volatile("s_waitcnt vmcnt(1)" ::: "memory");
            __builtin_amdgcn_s_barrier();
            __builtin_amdgcn_sched_barrier(0);
            const char* wsl = lds + WB_OFF + cur*8192 + q*2048;
            const char* hb  = (const char*)Hs + (p2*32 + q*8)*2;
            bf16x8 af0 = *(const bf16x8*)(hb + (wr*32 + lr)*272);
            bf16x8 af1 = *(const bf16x8*)(hb + (wr*32 + 16 + lr)*272);
            #pragma unroll
            for (int ni = 0; ni < 4; ni++){
                bf16x8 bf = *(const bf16x8*)(wsl + (wc*64 + ni*16 + lr)*16);
                ac2[0][ni] = __builtin_amdgcn_mfma_f32_16x16x32_bf16(af0, bf, ac2[0][ni], 0, 0, 0);
                ac2[1][ni] = __builtin_amdgcn_mfma_f32_16x16x32_bf16(af1, bf, ac2[1][ni], 0, 0, 0);
            }
            cur ^= 1;
        }
        // fused += gw[:,e] * (eo + b2)
        #pragma unroll
        for (int mi = 0; mi < 2; mi++){
            f32x4 gwv = *(const f32x4*)(lds + GWT_OFF + e*512 + (wr*32 + mi*16 + q*4)*4);
            #pragma unroll
            for (int ni = 0; ni < 4; ni++){
                int col = wc*64 + ni*16 + lr;
                float b2v = bf2f(b2L[e*128 + col]);
                #pragma unroll
                for (int j = 0; j < 4; j++)
                    fus[mi][ni][j] += gwv[j] * (ac2[mi][ni][j] + b2v);
            }
        }
    }

    asm volatile("s_waitcnt vmcnt(0)" ::: "memory");   // drain dummy stage
    __builtin_amdgcn_sched_barrier(0);
    __builtin_amdgcn_s_barrier();                      // all Hs(h7) reads done
    // fused -> Hs (bf16)
    #pragma unroll
    for (int mi = 0; mi < 2; mi++)
        #pragma unroll
        for (int ni = 0; ni < 4; ni++){
            int col = wc*64 + ni*16 + lr;
            #pragma unroll
            for (int j = 0; j < 4; j++){
                int row = wr*32 + mi*16 + q*4 + j;
                Hs[row*136 + col] = f2bf(fus[mi][ni][j]);
            }
        }
    asm volatile("s_waitcnt lgkmcnt(0)" ::: "memory");
    __builtin_amdgcn_sched_barrier(0);
    __builtin_amdgcn_s_barrier();

    // ---- penult = relu(fused @ pre_w + pre_b): wave wid -> rows wid*16..+16 ----
    f32x4 ap[4];
    #pragma unroll
    for (int i = 0; i < 4; i++) ap[i] = {0.f, 0.f, 0.f, 0.f};
    #pragma unroll
    for (int kt = 0; kt < 4; kt++){
        bf16x8 af = *(const bf16x8*)((const char*)Hs + (wid*16 + lr)*272 + (kt*32 + q*8)*2);
        #pragma unroll
        for (int ni = 0; ni < 4; ni++){
            bf16x8 bf = *(const bf16x8*)(prwT + (size_t)(ni*16 + lr)*128 + kt*32 + q*8);
            ap[ni] = __builtin_amdgcn_mfma_f32_16x16x32_bf16(af, bf, ap[ni], 0, 0, 0);
        }
    }
    float* Pen = (float*)lds;   // [128][68], Xs region dead
    #pragma unroll
    for (int ni = 0; ni < 4; ni++){
        int col = ni*16 + lr;
        float pbv = pre_b[col];
        #pragma unroll
        for (int j = 0; j < 4; j++){
            int row = wid*16 + q*4 + j;
            Pen[row*68 + col] = fmaxf(ap[ni][j] + pbv, 0.f);
        }
    }
    asm volatile("s_waitcnt lgkmcnt(0)" ::: "memory");
    __builtin_amdgcn_sched_barrier(0);
    __builtin_amdgcn_s_barrier();
    // ---- head ----
    if (tid < 256){
        int r = tid >> 1, c = tid & 1;
        float s = head_b[c];
        #pragma unroll 8
        for (int k = 0; k < 64; k++) s += Pen[r*68 + k] * head_w[k*2 + c];
        out[(size_t)(blk*128 + r)*2 + c] = s;
    }
}

extern "C" void kernel_launch(void* const* d_in, const int* in_sizes, int n_in,
                              void* d_out, int out_size, void* d_ws, size_t ws_size,
                              hipStream_t stream) {
    const float* ft     = (const float*)d_in[0];
    const float* fa     = (const float*)d_in[1];
    const float* fv     = (const float*)d_in[2];
    const float* proj_w = (const float*)d_in[3];
    const float* proj_b = (const float*)d_in[4];
    const float* exp_w1 = (const float*)d_in[5];
    const float* exp_b1 = (const float*)d_in[6];
    const float* exp_w2 = (const float*)d_in[7];
    const float* exp_b2 = (const float*)d_in[8];
    const float* gate_w = (const float*)d_in[9];
    const float* gate_b = (const float*)d_in[10];
    const float* pre_w  = (const float*)d_in[11];
    const float* pre_b  = (const float*)d_in[12];
    const float* head_w = (const float*)d_in[13];
    const float* head_b = (const float*)d_in[14];
    float* out = (float*)d_out;

    u16* xqimg = (u16*)d_ws;                      // 12582912 elems
    u16* pimg  = xqimg + (size_t)B_ROWS * 384;    // 294912
    u16* w1img = pimg + 294912;                   // 393216
    u16* w2img = w1img + 393216;                  // 131072
    u16* prwT  = w2img + 131072;                  // 8192
    u16* gwimg = prwT + 8192;                     // 6144

    cast_weights_kernel<<<3256, 256, 0, stream>>>(proj_w, exp_w1, exp_w2, pre_w, gate_w,
                                                  pimg, w1img, w2img, prwT, gwimg);
    proj_kernel<<<dim3(B_ROWS/64, 3), 256, 0, stream>>>(ft, fa, fv, pimg, proj_b, xqimg);
    moe_kernel<<<256, 512, 0, stream>>>(xqimg, w1img, w2img, prwT, gwimg,
                                        gate_b, exp_b1, exp_b2,
                                        pre_b, head_w, head_b, out);
}